// Round 8
// baseline (2297.508 us; speedup 1.0000x reference)
//
#include <hip/hip_runtime.h>

// Problem constants (from reference): B=256, NSEL=60000, NVERTS=100000, F=3
#define B_C      256
#define NSEL_C   60000
#define NV_C     100000
#define NBLK_P   ((NSEL_C + 255) / 256)   // 235 row-blocks per batch
#define SLICE    (NSEL_C * 3)             // floats per x batch slice
#define OUTSLICE (NV_C * 3)               // floats per out batch slice

typedef float f32x4 __attribute__((ext_vector_type(4)));

// ---------------- zero (nontemporal -> lines land CLEAN at memory) ----------------
// R7 lesson: plain cached zero stores leave out's 307 MB dirty in per-XCD
// L2s; subsequent device-scope atomics then force per-atomic flushes (1.44 GB
// HBM partial-line writes, 25x slowdown). Nontemporal stores bypass L2, so
// the atomic path sees clean lines (R6's fast regime: ~524 G atomics/s).
// 4 consecutive lanes x 16B = full 64B lines -> no partial-line amplification.
__global__ __launch_bounds__(256) void zero_out_nt_k(f32x4* __restrict__ out4, int n4) {
    int stride = gridDim.x * blockDim.x;
    f32x4 z = {0.f, 0.f, 0.f, 0.f};
    for (int i = blockIdx.x * blockDim.x + threadIdx.x; i < n4; i += stride)
        __builtin_nontemporal_store(z, out4 + i);
}

// ---------------- atomic scatter — VERBATIM R6 fallback structure ----------------
// grid (235, 256): j from blockIdx.x (coalesced x/vs reads), b = blockIdx.y.
// No XCD swizzle (R6's fast regime had none; don't re-bundle two changes).
// Randomness only in atomic DESTINATIONS: fire-and-forget RMWs, no dependent
// load chain — this beat every gather variant (R2-R5 ~200us read-latency wall).
__global__ __launch_bounds__(256) void scatter_atomic_k(const float* __restrict__ x,
                                                        const int* __restrict__ vs,
                                                        float* __restrict__ out) {
    int j = blockIdx.x * blockDim.x + threadIdx.x;
    int b = blockIdx.y;
    if (j < NSEL_C) {
        int v = vs[j];
        const float* p = x + ((size_t)b * NSEL_C + j) * 3;
        float* q = out + ((size_t)b * NV_C + v) * 3;
        atomicAdd(q + 0, p[0]);
        atomicAdd(q + 1, p[1]);
        atomicAdd(q + 2, p[2]);
    }
}

extern "C" void kernel_launch(void* const* d_in, const int* in_sizes, int n_in,
                              void* d_out, int out_size, void* d_ws, size_t ws_size,
                              hipStream_t stream) {
    const float* x  = (const float*)d_in[0];
    const int*   vs = (const int*)d_in[1];
    float* out = (float*)d_out;

    // 1) zero the output (76.8M floats = 19.2M f32x4; % 4 == 0, no tail)
    int n4 = out_size / 4;
    zero_out_nt_k<<<2048, 256, 0, stream>>>((f32x4*)out, n4);

    // 2) atomic scatter-add, R6 grid shape
    dim3 grid(NBLK_P, B_C);
    scatter_atomic_k<<<grid, 256, 0, stream>>>(x, vs, out);
}

// Round 9
// 214.866 us; speedup vs baseline: 10.6927x; 10.6927x over previous
//
#include <hip/hip_runtime.h>

// Problem constants (from reference): B=256, NSEL=60000, NVERTS=100000, F=3
#define B_C     256
#define NSEL_C  60000
#define NV_C    100000
#define SCAN_T  1024
#define NB1     ((NV_C + SCAN_T - 1) / SCAN_T)   // 98 scan blocks
#define NGRP    (NV_C / 4)                       // 25000 groups of 4 vertices
#define NBLK_G  ((NGRP + 255) / 256)             // 98 group-blocks per batch
#define NXCD    8
#define SLICE   (NSEL_C * 3)

typedef float f32x4 __attribute__((ext_vector_type(4)));
typedef int   i32x4 __attribute__((ext_vector_type(4)));

// ---------------- CSR build (identical to R3; ws = 1.84 MB, known to fit) ----

__global__ void zero_counts_k(int* __restrict__ counts) {
    int i = blockIdx.x * blockDim.x + threadIdx.x;
    if (i < NV_C) counts[i] = 0;
}

__global__ void hist_k(const int* __restrict__ vs, int* __restrict__ counts) {
    int j = blockIdx.x * blockDim.x + threadIdx.x;
    if (j < NSEL_C) atomicAdd(&counts[vs[j]], 1);
}

__global__ __launch_bounds__(SCAN_T) void scan1_k(const int* __restrict__ counts,
                                                  int* __restrict__ partial,
                                                  int* __restrict__ blockSums) {
    __shared__ int sm[SCAN_T];
    int tid = threadIdx.x;
    int i = blockIdx.x * SCAN_T + tid;
    int v = (i < NV_C) ? counts[i] : 0;
    int val = v;
    sm[tid] = val;
    __syncthreads();
    for (int off = 1; off < SCAN_T; off <<= 1) {
        int t = (tid >= off) ? sm[tid - off] : 0;
        __syncthreads();
        val += t;
        sm[tid] = val;
        __syncthreads();
    }
    if (i < NV_C) partial[i] = val - v;           // exclusive
    if (tid == SCAN_T - 1) blockSums[blockIdx.x] = val;
}

__global__ void scan2_k(const int* __restrict__ blockSums, int* __restrict__ blockOff) {
    if (blockIdx.x == 0 && threadIdx.x == 0) {
        int run = 0;
        for (int b = 0; b < NB1; ++b) { blockOff[b] = run; run += blockSums[b]; }
    }
}

__global__ void scan3_k(const int* __restrict__ partial, const int* __restrict__ blockOff,
                        int* __restrict__ offsets, int* __restrict__ cursor) {
    int i = blockIdx.x * blockDim.x + threadIdx.x;
    if (i < NV_C) {
        int o = partial[i] + blockOff[i / SCAN_T];
        offsets[i] = o;
        cursor[i]  = o;
    }
    if (i == 0) offsets[NV_C] = NSEL_C;
}

__global__ void fill_k(const int* __restrict__ vs, int* __restrict__ cursor,
                       int* __restrict__ list) {
    int j = blockIdx.x * blockDim.x + threadIdx.x;
    if (j < NSEL_C) {
        int v = vs[j];
        int pos = atomicAdd(&cursor[v], 1);
        list[pos] = 3 * j;                        // store 3*j directly
    }
}

// ---------------- gather: 4 vertices x 4 BATCHES per thread ----------------
// The random index list[k] is batch-independent: one list read feeds FOUR
// independent dwordx3 x-loads per iteration (4x useful bytes per dependent
// hop — the R2-R5 wall was latency/MSHR service of random 12B reads).
// 4 slices (2.9 MB) + offsets/list stay in the pinned XCD's 4MB L2.
// XCD swizzle: batch-quad bq only gets wg ids with id%8 == bq%8.
#define DECL_ACC(B) float B##00=0.f,B##01=0.f,B##02=0.f,B##10=0.f,B##11=0.f,B##12=0.f, \
                          B##20=0.f,B##21=0.f,B##22=0.f,B##30=0.f,B##31=0.f,B##32=0.f;
#define LOAD_ROW(B, ptr) float p##B##0 = ptr[eo], p##B##1 = ptr[eo+1], p##B##2 = ptr[eo+2];
#define ACC_ROW(B) \
    B##00 += i0 ? p##B##0 : 0.f;  B##01 += i0 ? p##B##1 : 0.f;  B##02 += i0 ? p##B##2 : 0.f; \
    B##10 += i1 ? p##B##0 : 0.f;  B##11 += i1 ? p##B##1 : 0.f;  B##12 += i1 ? p##B##2 : 0.f; \
    B##20 += i2 ? p##B##0 : 0.f;  B##21 += i2 ? p##B##1 : 0.f;  B##22 += i2 ? p##B##2 : 0.f; \
    B##30 += i3 ? p##B##0 : 0.f;  B##31 += i3 ? p##B##1 : 0.f;  B##32 += i3 ? p##B##2 : 0.f;
#define STORE_ROW(B, bidx) { \
    size_t ob = ((size_t)(bidx) * NV_C + v0) * 3; \
    f32x4 s0v = {B##00, B##01, B##02, B##10}; \
    f32x4 s1v = {B##11, B##12, B##20, B##21}; \
    f32x4 s2v = {B##22, B##30, B##31, B##32}; \
    *(f32x4*)(out + ob)     = s0v; \
    *(f32x4*)(out + ob + 4) = s1v; \
    *(f32x4*)(out + ob + 8) = s2v; }

__global__ __launch_bounds__(256) void gather4x4_k(const float* __restrict__ x,
                                                   const int* __restrict__ offsets,
                                                   const int* __restrict__ list,
                                                   float* __restrict__ out) {
    int lin  = blockIdx.x;               // [0, 64*NBLK_G)
    int xcd  = lin & (NXCD - 1);
    int rest = lin >> 3;                 // [0, 8*NBLK_G)
    int t    = rest % NBLK_G;
    int bq   = (rest / NBLK_G) * NXCD + xcd;   // batch-quad [0,64)
    int b0   = bq * 4;

    int g = t * 256 + threadIdx.x;       // group of 4 vertices
    if (g >= NGRP) return;
    int v0 = g * 4;

    i32x4 ov = *(const i32x4*)(offsets + v0);   // 16B-aligned
    int o0 = ov.x, o1 = ov.y, o2 = ov.z, o3 = ov.w;
    int o4 = offsets[v0 + 4];

    const float* xA = x + (size_t)(b0 + 0) * SLICE;
    const float* xB = x + (size_t)(b0 + 1) * SLICE;
    const float* xC = x + (size_t)(b0 + 2) * SLICE;
    const float* xD = x + (size_t)(b0 + 3) * SLICE;

    DECL_ACC(A) DECL_ACC(B) DECL_ACC(C) DECL_ACC(D)

    for (int k = o0; k < o4; ++k) {
        int eo = list[k];                // 3*j
        LOAD_ROW(A, xA) LOAD_ROW(B, xB) LOAD_ROW(C, xC) LOAD_ROW(D, xD)
        bool s1 = (k >= o1), s2 = (k >= o2), s3 = (k >= o3);
        bool i0 = !s1, i1 = s1 && !s2, i2 = s2 && !s3, i3 = s3;
        ACC_ROW(A) ACC_ROW(B) ACC_ROW(C) ACC_ROW(D)
    }

    STORE_ROW(A, b0 + 0)
    STORE_ROW(B, b0 + 1)
    STORE_ROW(C, b0 + 2)
    STORE_ROW(D, b0 + 3)
}

// ---------------- fallback: memset + atomic scatter (R6 regime) ----------------
__global__ __launch_bounds__(256) void scatter_atomic_k(const float* __restrict__ x,
                                                        const int* __restrict__ vs,
                                                        float* __restrict__ out) {
    int j = blockIdx.x * blockDim.x + threadIdx.x;
    int b = blockIdx.y;
    if (j < NSEL_C) {
        int v = vs[j];
        const float* p = x + ((size_t)b * NSEL_C + j) * 3;
        float* q = out + ((size_t)b * NV_C + v) * 3;
        atomicAdd(q + 0, p[0]);
        atomicAdd(q + 1, p[1]);
        atomicAdd(q + 2, p[2]);
    }
}

extern "C" void kernel_launch(void* const* d_in, const int* in_sizes, int n_in,
                              void* d_out, int out_size, void* d_ws, size_t ws_size,
                              hipStream_t stream) {
    const float* x  = (const float*)d_in[0];
    const int*   vs = (const int*)d_in[1];
    float* out = (float*)d_out;

    // ws layout (ints): counts[NV] | partial[NV] | offsets[NV+1] | cursor[NV]
    //                   | blockSums[NB1] | blockOff[NB1] | list[NSEL]  (1.84 MB)
    const size_t need_ints = (size_t)4 * NV_C + 1 + 2 * NB1 + NSEL_C;
    if (ws_size >= need_ints * sizeof(int)) {
        int* w        = (int*)d_ws;
        int* counts   = w;
        int* partial  = w + NV_C;
        int* offsets  = w + 2 * NV_C;          // NV_C + 1 entries
        int* cursor   = w + 3 * NV_C + 1;
        int* blockSums= w + 4 * NV_C + 1;
        int* blockOff = blockSums + NB1;
        int* list     = blockOff + NB1;

        zero_counts_k<<<(NV_C + 255) / 256, 256, 0, stream>>>(counts);
        hist_k<<<(NSEL_C + 255) / 256, 256, 0, stream>>>(vs, counts);
        scan1_k<<<NB1, SCAN_T, 0, stream>>>(counts, partial, blockSums);
        scan2_k<<<1, 64, 0, stream>>>(blockSums, blockOff);
        scan3_k<<<(NV_C + 255) / 256, 256, 0, stream>>>(partial, blockOff, offsets, cursor);
        fill_k<<<(NSEL_C + 255) / 256, 256, 0, stream>>>(vs, cursor, list);

        // 64 batch-quads x 98 group-blocks, XCD-swizzled (6272 % 8 == 0)
        gather4x4_k<<<64 * NBLK_G, 256, 0, stream>>>(x, offsets, list, out);
    } else {
        hipMemsetAsync(d_out, 0, (size_t)out_size * sizeof(float), stream);
        dim3 grid((NSEL_C + 255) / 256, B_C);
        scatter_atomic_k<<<grid, 256, 0, stream>>>(x, vs, out);
    }
}